// Round 14
// baseline (232.995 us; speedup 1.0000x reference)
//
#include <hip/hip_runtime.h>

#define N_TOK  8192
#define KDIM   4096
#define NE     16
#define NSLICE 8                   // k-slices -> ws partials per token
#define KS     512                 // k per slice
#define TPB    8                   // tokens per block (2 per wave)
#define GSTR   512                 // gateT expert-row stride in floats (32KB total)

// R20: barrier-free k-loop (R18's concept, correctly coded, jail-sized).
// R19 post-mortem: diet gave no win (logits ~63 vs R15's ~56; fixed-overhead
// model calibrated at ~131.5us via R18: 568.5-437). R18 re-audit: staging
// loop read 4x too much and wrote LDS OOB (k up to 8191 vs 2052) -> its
// failure was a BUG, not spill; barrier-free was never tested. Surviving
// theory: compiler emits s_waitcnt vmcnt(0) before EVERY s_barrier -> each
// chunk = [burst, full drain, barrier][compute, zero outstanding memory]
// -> ~40% HBM duty cycle == observed 2.4-2.6 TB/s. R20 removes in-loop
// barriers entirely: block stages a 32KB gate k-slice (512k x 16e,
// transposed) ONCE, then 2 chunks x 256k of pure {x-load, ds_read, FMA}
// with x loads issued upfront and full scheduler freedom (no barriers to
// block code motion). LDS 32KB -> 4 blocks/CU = 16 waves/CU. Demand:
// acc32 + x16 + transients ~64-72 (watch jail). ws = 8 slice partials (4MB).
// Prediction: logits -> 25-35us, BW 4-5 TB/s, VALUBusy 20-35%, WRITE ~4MB
// (no spill ballooning), total -> 160-172. Clean-but-flat => roofline next.
__global__ __launch_bounds__(256)
void router_logits(const float* __restrict__ x, const float* __restrict__ gate,
                   float* __restrict__ ws) {
  __shared__ __align__(16) float glds[NE * GSTR];  // 32 KB
  const int tid  = threadIdx.x;
  const int lane = tid & 63;
  const int w    = __builtin_amdgcn_readfirstlane(tid >> 6);
  const int g    = blockIdx.x >> 3;                // token group (1024)
  const int s    = blockIdx.x & 7;                 // k-slice -> ws slice
  const int t0   = g * TPB;
  const int tokb = t0 + w * 2;                     // wave's 2 tokens

  // ---- prologue: stage gate slice s (512 k x 16 e = 32 KB), transposed ----
  // 2048 f4 / 256 threads = 8 f4/thread (i in [0,2048): k=i>>2 in [0,512)).
  {
    const float4* gsrc = (const float4*)gate + (size_t)s * (KS * NE / 4);
    float4 gr[8];
#pragma unroll
    for (int u = 0; u < 8; ++u) gr[u] = gsrc[u * 256 + tid];
#pragma unroll
    for (int u = 0; u < 8; ++u) {
      int i = u * 256 + tid, k = i >> 2, j = i & 3;
      glds[(4 * j + 0) * GSTR + k] = gr[u].x;
      glds[(4 * j + 1) * GSTR + k] = gr[u].y;
      glds[(4 * j + 2) * GSTR + k] = gr[u].z;
      glds[(4 * j + 3) * GSTR + k] = gr[u].w;
    }
  }
  __syncthreads();                                 // gate resident (barrier #1)

  // ---- x loads: all 4 x 1KB contiguous wave-instrs issued upfront ----
  const float4* xr0 = (const float4*)(x + (size_t)(tokb + 0) * KDIM) + s * (KS / 4);
  const float4* xr1 = (const float4*)(x + (size_t)(tokb + 1) * KDIM) + s * (KS / 4);
  float4 xa0 = xr0[lane],      xa1 = xr1[lane];        // chunk 0
  float4 xb0 = xr0[64 + lane], xb1 = xr1[64 + lane];   // chunk 1

  float acc[2][NE];
#pragma unroll
  for (int t = 0; t < 2; ++t)
#pragma unroll
    for (int e = 0; e < NE; ++e) acc[t][e] = 0.f;

  const float4* gl4 = (const float4*)glds;         // expert e -> gl4[e*128 ..]

  // ---- barrier-free k-loop: 2 chunks x 256 k ----
#pragma unroll
  for (int c = 0; c < 2; ++c) {
    const float4 x0 = (c == 0) ? xa0 : xb0;
    const float4 x1 = (c == 0) ? xa1 : xb1;
#pragma unroll
    for (int eq = 0; eq < 4; ++eq) {
      const float4 ge0 = gl4[(eq * 4 + 0) * 128 + c * 64 + lane];
      const float4 ge1 = gl4[(eq * 4 + 1) * 128 + c * 64 + lane];
      const float4 ge2 = gl4[(eq * 4 + 2) * 128 + c * 64 + lane];
      const float4 ge3 = gl4[(eq * 4 + 3) * 128 + c * 64 + lane];
      acc[0][eq*4+0] += x0.x*ge0.x + x0.y*ge0.y + x0.z*ge0.z + x0.w*ge0.w;
      acc[0][eq*4+1] += x0.x*ge1.x + x0.y*ge1.y + x0.z*ge1.z + x0.w*ge1.w;
      acc[0][eq*4+2] += x0.x*ge2.x + x0.y*ge2.y + x0.z*ge2.z + x0.w*ge2.w;
      acc[0][eq*4+3] += x0.x*ge3.x + x0.y*ge3.y + x0.z*ge3.z + x0.w*ge3.w;
      acc[1][eq*4+0] += x1.x*ge0.x + x1.y*ge0.y + x1.z*ge0.z + x1.w*ge0.w;
      acc[1][eq*4+1] += x1.x*ge1.x + x1.y*ge1.y + x1.z*ge1.z + x1.w*ge1.w;
      acc[1][eq*4+2] += x1.x*ge2.x + x1.y*ge2.y + x1.z*ge2.z + x1.w*ge2.w;
      acc[1][eq*4+3] += x1.x*ge3.x + x1.y*ge3.y + x1.z*ge3.z + x1.w*ge3.w;
    }
  }

  // ---- epilogue: butterfly (k over lanes) + cross-wave gather ----
#pragma unroll
  for (int t = 0; t < 2; ++t)
#pragma unroll
    for (int e = 0; e < NE; ++e) {
      acc[t][e] += __shfl_xor(acc[t][e], 32, 64);
      acc[t][e] += __shfl_xor(acc[t][e], 16, 64);
      acc[t][e] += __shfl_xor(acc[t][e],  8, 64);
    }
  __syncthreads();                                 // all ds_reads done (#2)
  if (lane < 8) {                                  // reuse glds[0..1023]
#pragma unroll
    for (int t = 0; t < 2; ++t)
#pragma unroll
      for (int e = 0; e < NE; ++e)
        glds[((w * 8 + lane) * 2 + t) * 16 + e] = acc[t][e];
  }
  __syncthreads();                                 // (#3)
  if (tid < 128) {                                 // 8 tokens x 16 e
    int tok = tid >> 4, e = tid & 15;
    int ww = tok >> 1, tt = tok & 1;
    float sum = 0.f;
#pragma unroll
    for (int grp = 0; grp < 8; ++grp)
      sum += glds[((ww * 8 + grp) * 2 + tt) * 16 + e];
    ws[((size_t)s * N_TOK + t0 + tok) * NE + e] = sum;   // 512B/block, coalesced
  }
}

// Sum 8 slice partials, top-2 (earliest-index tie-break = jax top_k),
// sigmoid, scatter into (E,N) scores; token_indices[e][t] = t (as float).
__global__ __launch_bounds__(256)
void router_finalize(const float* __restrict__ ws, float* __restrict__ out) {
  int t = blockIdx.x * 256 + threadIdx.x;
  float l[NE];
#pragma unroll
  for (int e = 0; e < NE; ++e) l[e] = 0.f;
#pragma unroll
  for (int s = 0; s < NSLICE; ++s) {
    const float4* row = (const float4*)(ws + ((size_t)s * N_TOK + t) * NE);
    float4 r0 = row[0], r1 = row[1], r2 = row[2], r3 = row[3];
    l[0]  += r0.x; l[1]  += r0.y; l[2]  += r0.z; l[3]  += r0.w;
    l[4]  += r1.x; l[5]  += r1.y; l[6]  += r1.z; l[7]  += r1.w;
    l[8]  += r2.x; l[9]  += r2.y; l[10] += r2.z; l[11] += r2.w;
    l[12] += r3.x; l[13] += r3.y; l[14] += r3.z; l[15] += r3.w;
  }
  int i1 = 0; float v1 = l[0];
#pragma unroll
  for (int e = 1; e < NE; ++e) { if (l[e] > v1) { v1 = l[e]; i1 = e; } }
  int i2 = -1; float v2 = -1e30f;
#pragma unroll
  for (int e = 0; e < NE; ++e) { if (e != i1 && l[e] > v2) { v2 = l[e]; i2 = e; } }
  float s1 = 1.f / (1.f + __expf(-v1));
  float s2 = 1.f / (1.f + __expf(-v2));
  float* scores = out;
  float* tix    = out + (size_t)NE * N_TOK;
  float tf = (float)t;
#pragma unroll
  for (int e = 0; e < NE; ++e) {                   // coalesced across lanes per e
    scores[(size_t)e * N_TOK + t] = (e == i1) ? s1 : ((e == i2) ? s2 : 0.f);
    tix[(size_t)e * N_TOK + t]    = tf;
  }
}

extern "C" void kernel_launch(void* const* d_in, const int* in_sizes, int n_in,
                              void* d_out, int out_size, void* d_ws, size_t ws_size,
                              hipStream_t stream) {
  const float* x    = (const float*)d_in[0];
  const float* gate = (const float*)d_in[1];
  float* out = (float*)d_out;
  float* ws  = (float*)d_ws;   // needs NSLICE*N_TOK*NE*4 = 4 MB
  router_logits<<<dim3(N_TOK / TPB * NSLICE), dim3(256), 0, stream>>>(x, gate, ws);
  router_finalize<<<dim3(N_TOK / 256), dim3(256), 0, stream>>>(ws, out);
}